// Round 3
// baseline (458.410 us; speedup 1.0000x reference)
//
#include <hip/hip_runtime.h>

// B,H,N,D,E = 2,8,512,16,128
constexpr int CB = 2;
constexpr int CH = 8;
constexpr int CN = 512;
constexpr int CD = 16;
constexpr int CE = 128;
constexpr int CHD = CH * CD;   // 128
constexpr int TM = 32;         // m-rows per z tile
constexpr int NTILE = CN / TM; // 16
constexpr int NT = 256;        // 4 waves

typedef __attribute__((ext_vector_type(8))) short short8;   // 8 bf16 (MFMA A/B frag)
typedef __attribute__((ext_vector_type(4))) float f32x4;    // MFMA C/D frag

__device__ __forceinline__ unsigned short f2bf_rne(float x) {
  union { float f; unsigned int u; } a; a.f = x;
  unsigned int r = a.u + 0x7fffu + ((a.u >> 16) & 1u);
  return (unsigned short)(r >> 16);
}

// Truncation split: hi = top 16 bits (exact bf16), lo = (x - hi) truncated to bf16.
__device__ __forceinline__ void split_pair(float x0, float x1,
                                           unsigned int& hi, unsigned int& lo) {
  unsigned int u0 = __float_as_uint(x0), u1 = __float_as_uint(x1);
  unsigned int h0 = u0 & 0xffff0000u, h1 = u1 & 0xffff0000u;
  float l0 = x0 - __uint_as_float(h0);
  float l1 = x1 - __uint_as_float(h1);
  hi = h1 | (u0 >> 16);
  lo = (__float_as_uint(l1) & 0xffff0000u) | (__float_as_uint(l0) >> 16);
}

// 8 consecutive floats (a then b) -> 8 bf16 hi + 8 bf16 lo, memory order.
__device__ __forceinline__ void split8(const float4 a, const float4 b,
                                       short8& hi, short8& lo) {
  union { unsigned int u[4]; short8 s; } H, L;
  split_pair(a.x, a.y, H.u[0], L.u[0]);
  split_pair(a.z, a.w, H.u[1], L.u[1]);
  split_pair(b.x, b.y, H.u[2], L.u[2]);
  split_pair(b.z, b.w, H.u[3], L.u[3]);
  hi = H.s; lo = L.s;
}

#define MFMA(A, B, C) __builtin_amdgcn_mfma_f32_16x16x32_bf16((A), (B), (C), 0, 0, 0)

// Transposed-product scheme: MFMA(W_frag, z_frag, acc) computes (z @ W)^T with
// C row = d (quad*4+reg), col = m (lane&15): coalesced k/v float4 loads, cheap
// d-reduction (xor16/32 only).
//
// LDS: SINGLE-buffered 16 KB z tile (hi/lo bf16), two barriers per tile.
// Occupancy experiment: 32 KB/block capped residency at 2 blocks/CU (measured
// 25.6% occupancy, stable across rounds); 16 KB should allow the full
// grid-provided 4 blocks/CU. Tile t+1 is carried across the barrier in
// registers (zr0..3), so pipeline depth is unchanged.
__global__ __launch_bounds__(NT, 3) void fused_mixedscore_attn(
    const float* __restrict__ q, const float* __restrict__ kk,
    const float* __restrict__ v, const float* __restrict__ z,
    const float* __restrict__ W1, const float* __restrict__ W2,
    float* __restrict__ out)
{
  const int n = blockIdx.x;
  const int b = blockIdx.y;
  const int tid = threadIdx.x;
  const int lane = tid & 63;
  const int wave = tid >> 6;      // owns heads {2w, 2w+1}
  const int col = lane & 15;      // C col = m-offset
  const int quad = lane >> 4;     // C row-group = d-group
  const int h0 = wave * 2;

  __shared__ unsigned short zh[TM * CE];   // hi bf16, 8 KB
  __shared__ unsigned short zl[TM * CE];   // lo bf16, 8 KB

  const float* gz = z + (size_t)(b * CN + n) * CN * CE;

  // staging: thread handles row sr, 16 consecutive floats starting at sc
  const int sr = tid >> 3;          // 0..31
  const int sc = (tid & 7) * 16;    // 0..112
  const int wb0 = sr * 256 + ((sc * 2) ^ ((sr & 7) << 4));
  const int wb1 = sr * 256 + ((sc * 2 + 16) ^ ((sr & 7) << 4));

  // ---- issue tile-0 loads first (latency hides under W/q setup) ----
  float4 zr0, zr1, zr2, zr3;
  {
    const float* g0 = gz + sr * CE + sc;
    zr0 = *(const float4*)(g0);
    zr1 = *(const float4*)(g0 + 4);
    zr2 = *(const float4*)(g0 + 8);
    zr3 = *(const float4*)(g0 + 12);
  }

  // ---- W1,W2 -> bf16 RNE fragments, held in VGPRs all kernel ----
  short8 B1[2][4], B2[2][4];   // [head][ks]
#pragma unroll
  for (int ct = 0; ct < 2; ++ct) {
    const int c = (h0 + ct) * CD + col;
#pragma unroll
    for (int ks = 0; ks < 4; ++ks) {
      union { unsigned int u[4]; short8 s; } U1, U2;
#pragma unroll
      for (int jp = 0; jp < 4; ++jp) {
        const int e = ks * 32 + quad * 8 + jp * 2;
        const float a0 = W1[(size_t)e * CHD + c];
        const float a1 = W1[(size_t)(e + 1) * CHD + c];
        const float w0 = W2[(size_t)e * CHD + c];
        const float w1 = W2[(size_t)(e + 1) * CHD + c];
        U1.u[jp] = (unsigned int)f2bf_rne(a0) | ((unsigned int)f2bf_rne(a1) << 16);
        U2.u[jp] = (unsigned int)f2bf_rne(w0) | ((unsigned int)f2bf_rne(w1) << 16);
      }
      B1[ct][ks] = U1.s;
      B2[ct][ks] = U2.s;
    }
  }

  // q for this n: lane needs d = quad*4..+3 per head -> float4
  float4 qv[2];
  qv[0] = *(const float4*)&q[((size_t)(b * CH + h0) * CN + n) * CD + quad * 4];
  qv[1] = *(const float4*)&q[((size_t)(b * CH + h0 + 1) * CN + n) * CD + quad * 4];

  // online-softmax state (wave-uniform) + per-lane O partials over m in {col+16mt+32t}
  f32x4 Oa[2] = {f32x4{0.f, 0.f, 0.f, 0.f}, f32x4{0.f, 0.f, 0.f, 0.f}};
  float mrun[2] = {-3.0e38f, -3.0e38f};
  float srun[2] = {0.f, 0.f};

  for (int t = 0; t < NTILE; ++t) {
    const int m0 = t * TM;

    // ---- cooperative split: fp32 regs -> bf16 hi/lo LDS ----
    {
      char* zhb = (char*)&zh[0];
      char* zlb = (char*)&zl[0];
      short8 h8, l8;
      split8(zr0, zr1, h8, l8);
      *(short8*)(zhb + wb0) = h8;
      *(short8*)(zlb + wb0) = l8;
      split8(zr2, zr3, h8, l8);
      *(short8*)(zhb + wb1) = h8;
      *(short8*)(zlb + wb1) = l8;
    }
    __syncthreads();   // barrier1: tile-t writes visible before reads

    // ---- issue tile t+1 loads; they fly under the whole compute phase ----
    if (t + 1 < NTILE) {
      const float* g1 = gz + ((size_t)(t + 1) * TM + sr) * CE + sc;
      zr0 = *(const float4*)(g1);
      zr1 = *(const float4*)(g1 + 4);
      zr2 = *(const float4*)(g1 + 8);
      zr3 = *(const float4*)(g1 + 12);
    }

    // ---- transposed split-bf16 MFMA: acc[d][m] = (z@W)^T ----
    f32x4 acc1[2][2], acc2[2][2];   // [mt][head]
#pragma unroll
    for (int mt = 0; mt < 2; ++mt)
#pragma unroll
      for (int ct = 0; ct < 2; ++ct) {
        acc1[mt][ct] = f32x4{0.f, 0.f, 0.f, 0.f};
        acc2[mt][ct] = f32x4{0.f, 0.f, 0.f, 0.f};
      }

    const char* zhb = (const char*)&zh[0];
    const char* zlb = (const char*)&zl[0];
    __builtin_amdgcn_s_setprio(1);
#pragma unroll
    for (int ks = 0; ks < 4; ++ks) {
#pragma unroll
      for (int mt = 0; mt < 2; ++mt) {
        const int row = mt * 16 + col;
        const int off = row * 256 + ((ks * 64 + quad * 16) ^ ((row & 7) << 4));
        const short8 ah = *(const short8*)(zhb + off);
        const short8 al = *(const short8*)(zlb + off);
        acc1[mt][0] = MFMA(B1[0][ks], ah, acc1[mt][0]);
        acc1[mt][1] = MFMA(B1[1][ks], ah, acc1[mt][1]);
        acc2[mt][0] = MFMA(B2[0][ks], ah, acc2[mt][0]);
        acc2[mt][1] = MFMA(B2[1][ks], ah, acc2[mt][1]);
        acc1[mt][0] = MFMA(B1[0][ks], al, acc1[mt][0]);
        acc1[mt][1] = MFMA(B1[1][ks], al, acc1[mt][1]);
        acc2[mt][0] = MFMA(B2[0][ks], al, acc2[mt][0]);
        acc2[mt][1] = MFMA(B2[1][ks], al, acc2[mt][1]);
      }
    }
    __builtin_amdgcn_s_setprio(0);

    // ---- scores: lane holds 4 d-components for m = m0+mt*16+col ----
    float sc2[2][2];
#pragma unroll
    for (int mt = 0; mt < 2; ++mt) {
      const int m = m0 + mt * 16 + col;
#pragma unroll
      for (int ct = 0; ct < 2; ++ct) {
        const float4 k4 =
            *(const float4*)&kk[((size_t)(b * CH + h0 + ct) * CN + m) * CD + quad * 4];
        float p = (qv[ct].x + acc1[mt][ct][0]) * (k4.x + acc2[mt][ct][0]);
        p += (qv[ct].y + acc1[mt][ct][1]) * (k4.y + acc2[mt][ct][1]);
        p += (qv[ct].z + acc1[mt][ct][2]) * (k4.z + acc2[mt][ct][2]);
        p += (qv[ct].w + acc1[mt][ct][3]) * (k4.w + acc2[mt][ct][3]);
        p += __shfl_xor(p, 16);
        p += __shfl_xor(p, 32);
        sc2[mt][ct] = p * 0.25f;   // replicated across the quad's 16 lanes
      }
    }

    // ---- online softmax + PV (v loads are coalesced float4) ----
#pragma unroll
    for (int ct = 0; ct < 2; ++ct) {
      float tmax = fmaxf(sc2[0][ct], sc2[1][ct]);
      tmax = fmaxf(tmax, __shfl_xor(tmax, 1));
      tmax = fmaxf(tmax, __shfl_xor(tmax, 2));
      tmax = fmaxf(tmax, __shfl_xor(tmax, 4));
      tmax = fmaxf(tmax, __shfl_xor(tmax, 8));
      const float mnew = fmaxf(mrun[ct], tmax);
      const float alpha = __expf(mrun[ct] - mnew);
      mrun[ct] = mnew;
      const float e0 = __expf(sc2[0][ct] - mnew);
      const float e1 = __expf(sc2[1][ct] - mnew);
      float ls = e0 + e1;
      ls += __shfl_xor(ls, 1);
      ls += __shfl_xor(ls, 2);
      ls += __shfl_xor(ls, 4);
      ls += __shfl_xor(ls, 8);
      srun[ct] = srun[ct] * alpha + ls;

      const float* vb = v + ((size_t)(b * CH + h0 + ct) * CN) * CD + quad * 4;
      const float4 v0 = *(const float4*)&vb[(size_t)(m0 + col) * CD];
      const float4 v1 = *(const float4*)&vb[(size_t)(m0 + 16 + col) * CD];
      Oa[ct][0] = Oa[ct][0] * alpha + e0 * v0.x + e1 * v1.x;
      Oa[ct][1] = Oa[ct][1] * alpha + e0 * v0.y + e1 * v1.y;
      Oa[ct][2] = Oa[ct][2] * alpha + e0 * v0.z + e1 * v1.z;
      Oa[ct][3] = Oa[ct][3] * alpha + e0 * v0.w + e1 * v1.w;
    }

    // barrier2: all waves' LDS reads for tile t done before tile t+1 overwrites
    if (t + 1 < NTILE) __syncthreads();
  }

  // ---- finalize: reduce O partials across the 16 m-cols, normalize, store ----
#pragma unroll
  for (int ct = 0; ct < 2; ++ct) {
#pragma unroll
    for (int rg = 0; rg < 4; ++rg) {
      float o = Oa[ct][rg];
      o += __shfl_xor(o, 1);
      o += __shfl_xor(o, 2);
      o += __shfl_xor(o, 4);
      o += __shfl_xor(o, 8);
      Oa[ct][rg] = o;
    }
    if (col == 0) {
      const float inv = 1.0f / srun[ct];
      float4 o4;
      o4.x = Oa[ct][0] * inv;
      o4.y = Oa[ct][1] * inv;
      o4.z = Oa[ct][2] * inv;
      o4.w = Oa[ct][3] * inv;
      *(float4*)&out[(size_t)(b * CN + n) * CHD + (h0 + ct) * CD + quad * 4] = o4;
    }
  }
}

extern "C" void kernel_launch(void* const* d_in, const int* in_sizes, int n_in,
                              void* d_out, int out_size, void* d_ws, size_t ws_size,
                              hipStream_t stream) {
  const float* q  = (const float*)d_in[0];
  const float* kv = (const float*)d_in[1];
  const float* v  = (const float*)d_in[2];
  const float* z  = (const float*)d_in[3];
  const float* W1 = (const float*)d_in[4];
  const float* W2 = (const float*)d_in[5];
  float* out = (float*)d_out;
  (void)in_sizes; (void)n_in; (void)out_size; (void)d_ws; (void)ws_size;

  dim3 grid(CN, CB);
  hipLaunchKernelGGL(fused_mixedscore_attn, grid, dim3(NT), 0, stream,
                     q, kv, v, z, W1, W2, out);
}

// Round 4
// 376.812 us; speedup vs baseline: 1.2165x; 1.2165x over previous
//
#include <hip/hip_runtime.h>

// B,H,N,D,E = 2,8,512,16,128
constexpr int CB = 2;
constexpr int CH = 8;
constexpr int CN = 512;
constexpr int CD = 16;
constexpr int CE = 128;
constexpr int CHD = CH * CD;   // 128
constexpr int TM = 32;         // m-rows per z tile
constexpr int NTILE = CN / TM; // 16
constexpr int NT = 512;        // 8 waves, one head per wave

typedef __attribute__((ext_vector_type(8))) short short8;   // 8 bf16 (MFMA A/B frag)
typedef __attribute__((ext_vector_type(4))) float f32x4;    // MFMA C/D frag

__device__ __forceinline__ unsigned short f2bf_rne(float x) {
  union { float f; unsigned int u; } a; a.f = x;
  unsigned int r = a.u + 0x7fffu + ((a.u >> 16) & 1u);
  return (unsigned short)(r >> 16);
}

// Truncation split: hi = top 16 bits (exact bf16), lo = (x - hi) truncated to bf16.
__device__ __forceinline__ void split_pair(float x0, float x1,
                                           unsigned int& hi, unsigned int& lo) {
  unsigned int u0 = __float_as_uint(x0), u1 = __float_as_uint(x1);
  unsigned int h0 = u0 & 0xffff0000u, h1 = u1 & 0xffff0000u;
  float l0 = x0 - __uint_as_float(h0);
  float l1 = x1 - __uint_as_float(h1);
  hi = h1 | (u0 >> 16);
  lo = (__float_as_uint(l1) & 0xffff0000u) | (__float_as_uint(l0) >> 16);
}

// 8 consecutive floats (a then b) -> 8 bf16 hi + 8 bf16 lo, memory order.
__device__ __forceinline__ void split8(const float4 a, const float4 b,
                                       short8& hi, short8& lo) {
  union { unsigned int u[4]; short8 s; } H, L;
  split_pair(a.x, a.y, H.u[0], L.u[0]);
  split_pair(a.z, a.w, H.u[1], L.u[1]);
  split_pair(b.x, b.y, H.u[2], L.u[2]);
  split_pair(b.z, b.w, H.u[3], L.u[3]);
  hi = H.s; lo = L.s;
}

#define MFMA(A, B, C) __builtin_amdgcn_mfma_f32_16x16x32_bf16((A), (B), (C), 0, 0, 0)

// Round-2 pipeline (double-buffered LDS, ONE barrier per tile) + 8-wave blocks.
// Occupancy was pinned at ~2 blocks/CU independent of LDS (R3 experiment), so we
// pack 8 waves per block (1 head per wave): 2 blocks/CU -> 16 waves/CU instead
// of 8. Per-wave work halves (staging split 512-way, 32 MFMA/tile, one softmax
// chain). Transposed MFMA: MFMA(W_frag, z_frag) = (z@W)^T, C row = d, col = m.
__global__ __launch_bounds__(NT, 4) void fused_mixedscore_attn(
    const float* __restrict__ q, const float* __restrict__ kk,
    const float* __restrict__ v, const float* __restrict__ z,
    const float* __restrict__ W1, const float* __restrict__ W2,
    float* __restrict__ out)
{
  const int n = blockIdx.x;
  const int b = blockIdx.y;
  const int tid = threadIdx.x;
  const int lane = tid & 63;
  const int h = tid >> 6;         // wave = head
  const int col = lane & 15;      // C col = m-offset
  const int quad = lane >> 4;     // C row-group = d-group

  __shared__ unsigned short zh[2][TM * CE];   // hi bf16, dbuf, 16 KB
  __shared__ unsigned short zl[2][TM * CE];   // lo bf16, dbuf, 16 KB

  const float* gz = z + (size_t)(b * CN + n) * CN * CE;

  // staging: thread handles row sr, 8 consecutive floats starting at sc
  const int sr = tid >> 4;          // 0..31
  const int sc = (tid & 15) * 8;    // 0..120
  const int wb = sr * 256 + ((sc * 2) ^ ((sr & 7) << 4));

  // ---- issue tile-0 loads first (latency hides under W/q setup) ----
  float4 zr0, zr1;
  {
    const float* g0 = gz + sr * CE + sc;
    zr0 = *(const float4*)(g0);
    zr1 = *(const float4*)(g0 + 4);
  }

  // ---- W1,W2 -> bf16 RNE fragments for this wave's head ----
  short8 B1[4], B2[4];   // [ks]
  {
    const int c = h * CD + col;
#pragma unroll
    for (int ks = 0; ks < 4; ++ks) {
      union { unsigned int u[4]; short8 s; } U1, U2;
#pragma unroll
      for (int jp = 0; jp < 4; ++jp) {
        const int e = ks * 32 + quad * 8 + jp * 2;
        const float a0 = W1[(size_t)e * CHD + c];
        const float a1 = W1[(size_t)(e + 1) * CHD + c];
        const float w0 = W2[(size_t)e * CHD + c];
        const float w1 = W2[(size_t)(e + 1) * CHD + c];
        U1.u[jp] = (unsigned int)f2bf_rne(a0) | ((unsigned int)f2bf_rne(a1) << 16);
        U2.u[jp] = (unsigned int)f2bf_rne(w0) | ((unsigned int)f2bf_rne(w1) << 16);
      }
      B1[ks] = U1.s;
      B2[ks] = U2.s;
    }
  }

  // q for this (n, h): lane needs d = quad*4..+3
  const float4 qv =
      *(const float4*)&q[((size_t)(b * CH + h) * CN + n) * CD + quad * 4];

  // online-softmax state (wave-uniform) + per-lane O partials
  f32x4 Oa = f32x4{0.f, 0.f, 0.f, 0.f};
  float mrun = -3.0e38f;
  float srun = 0.f;

  for (int t = 0; t < NTILE; ++t) {
    const int cb = t & 1;
    const int m0 = t * TM;

    // ---- cooperative split: fp32 regs -> bf16 hi/lo LDS (512 threads) ----
    {
      short8 h8, l8;
      split8(zr0, zr1, h8, l8);
      *(short8*)((char*)&zh[cb][0] + wb) = h8;
      *(short8*)((char*)&zl[cb][0] + wb) = l8;
    }
    __syncthreads();   // single barrier per tile: writes(t) before reads(t);
                       // one-tile wave skew is safe with the double buffer

    // ---- issue tile t+1 loads; they fly under the whole compute phase ----
    if (t + 1 < NTILE) {
      const float* g1 = gz + ((size_t)(t + 1) * TM + sr) * CE + sc;
      zr0 = *(const float4*)(g1);
      zr1 = *(const float4*)(g1 + 4);
    }

    // ---- transposed split-bf16 MFMA: acc[d][m] = (z@W)^T for head h ----
    f32x4 acc1[2], acc2[2];   // [mt]
#pragma unroll
    for (int mt = 0; mt < 2; ++mt) {
      acc1[mt] = f32x4{0.f, 0.f, 0.f, 0.f};
      acc2[mt] = f32x4{0.f, 0.f, 0.f, 0.f};
    }

    const char* zhb = (const char*)&zh[cb][0];
    const char* zlb = (const char*)&zl[cb][0];
#pragma unroll
    for (int ks = 0; ks < 4; ++ks) {
#pragma unroll
      for (int mt = 0; mt < 2; ++mt) {
        const int row = mt * 16 + col;
        const int off = row * 256 + ((ks * 64 + quad * 16) ^ ((row & 7) << 4));
        const short8 ah = *(const short8*)(zhb + off);
        const short8 al = *(const short8*)(zlb + off);
        acc1[mt] = MFMA(B1[ks], ah, acc1[mt]);
        acc2[mt] = MFMA(B2[ks], ah, acc2[mt]);
        acc1[mt] = MFMA(B1[ks], al, acc1[mt]);
        acc2[mt] = MFMA(B2[ks], al, acc2[mt]);
      }
    }

    // ---- scores: lane holds 4 d-components for m = m0+mt*16+col ----
    float sc2[2];
#pragma unroll
    for (int mt = 0; mt < 2; ++mt) {
      const int m = m0 + mt * 16 + col;
      const float4 k4 =
          *(const float4*)&kk[((size_t)(b * CH + h) * CN + m) * CD + quad * 4];
      float p = (qv.x + acc1[mt][0]) * (k4.x + acc2[mt][0]);
      p += (qv.y + acc1[mt][1]) * (k4.y + acc2[mt][1]);
      p += (qv.z + acc1[mt][2]) * (k4.z + acc2[mt][2]);
      p += (qv.w + acc1[mt][3]) * (k4.w + acc2[mt][3]);
      p += __shfl_xor(p, 16);
      p += __shfl_xor(p, 32);
      sc2[mt] = p * 0.25f;   // replicated across the quad's 16 lanes
    }

    // ---- online softmax + PV (v loads are coalesced float4) ----
    {
      float tmax = fmaxf(sc2[0], sc2[1]);
      tmax = fmaxf(tmax, __shfl_xor(tmax, 1));
      tmax = fmaxf(tmax, __shfl_xor(tmax, 2));
      tmax = fmaxf(tmax, __shfl_xor(tmax, 4));
      tmax = fmaxf(tmax, __shfl_xor(tmax, 8));
      const float mnew = fmaxf(mrun, tmax);
      const float alpha = __expf(mrun - mnew);
      mrun = mnew;
      const float e0 = __expf(sc2[0] - mnew);
      const float e1 = __expf(sc2[1] - mnew);
      float ls = e0 + e1;
      ls += __shfl_xor(ls, 1);
      ls += __shfl_xor(ls, 2);
      ls += __shfl_xor(ls, 4);
      ls += __shfl_xor(ls, 8);
      srun = srun * alpha + ls;

      const float* vb = v + ((size_t)(b * CH + h) * CN) * CD + quad * 4;
      const float4 v0 = *(const float4*)&vb[(size_t)(m0 + col) * CD];
      const float4 v1 = *(const float4*)&vb[(size_t)(m0 + 16 + col) * CD];
      Oa[0] = Oa[0] * alpha + e0 * v0.x + e1 * v1.x;
      Oa[1] = Oa[1] * alpha + e0 * v0.y + e1 * v1.y;
      Oa[2] = Oa[2] * alpha + e0 * v0.z + e1 * v1.z;
      Oa[3] = Oa[3] * alpha + e0 * v0.w + e1 * v1.w;
    }
  }

  // ---- finalize: reduce O partials across the 16 m-cols, normalize, store ----
#pragma unroll
  for (int rg = 0; rg < 4; ++rg) {
    float o = Oa[rg];
    o += __shfl_xor(o, 1);
    o += __shfl_xor(o, 2);
    o += __shfl_xor(o, 4);
    o += __shfl_xor(o, 8);
    Oa[rg] = o;
  }
  if (col == 0) {
    const float inv = 1.0f / srun;
    float4 o4;
    o4.x = Oa[0] * inv;
    o4.y = Oa[1] * inv;
    o4.z = Oa[2] * inv;
    o4.w = Oa[3] * inv;
    *(float4*)&out[(size_t)(b * CN + n) * CHD + h * CD + quad * 4] = o4;
  }
}

extern "C" void kernel_launch(void* const* d_in, const int* in_sizes, int n_in,
                              void* d_out, int out_size, void* d_ws, size_t ws_size,
                              hipStream_t stream) {
  const float* q  = (const float*)d_in[0];
  const float* kv = (const float*)d_in[1];
  const float* v  = (const float*)d_in[2];
  const float* z  = (const float*)d_in[3];
  const float* W1 = (const float*)d_in[4];
  const float* W2 = (const float*)d_in[5];
  float* out = (float*)d_out;
  (void)in_sizes; (void)n_in; (void)out_size; (void)d_ws; (void)ws_size;

  dim3 grid(CN, CB);
  hipLaunchKernelGGL(fused_mixedscore_attn, grid, dim3(NT), 0, stream,
                     q, kv, v, z, W1, W2, out);
}